// Round 5
// baseline (229.217 us; speedup 1.0000x reference)
//
#include <hip/hip_runtime.h>
#include <hip/hip_bf16.h>

#define NN 100000
#define NE 800000
#define FIN 96
#define FH 128
#define FC 64

#define BLOW 9            // 512 dsts per bucket
#define NBK 196           // ceil(NN/512)
#define BCAP 5120         // bucket capacity (avg 4096, sd ~64)
#define P1E 4096          // edges per bin block
#define NB_CVTX ((NN * FIN / 8 + 255) / 256)   // 4688 (8 floats/thread)

typedef unsigned short u16;
typedef unsigned int u32;
typedef __attribute__((ext_vector_type(8))) __bf16 bf16x8;
typedef __attribute__((ext_vector_type(4))) float f32x4;

__device__ __forceinline__ float bf2f(u16 u) {
    u32 x = ((u32)u) << 16;
    return __builtin_bit_cast(float, x);
}
__device__ __forceinline__ u16 f2bf(float f) {
    u32 u = __builtin_bit_cast(u32, f);
    u += 0x7fffu + ((u >> 16) & 1u);
    return (u16)(u >> 16);
}
__device__ __forceinline__ void load8f(const u16* p, float* o) {
    uint4 pk = *(const uint4*)p;
    o[0] = bf2f((u16)pk.x); o[1] = bf2f((u16)(pk.x >> 16));
    o[2] = bf2f((u16)pk.y); o[3] = bf2f((u16)(pk.y >> 16));
    o[4] = bf2f((u16)pk.z); o[5] = bf2f((u16)(pk.z >> 16));
    o[6] = bf2f((u16)pk.w); o[7] = bf2f((u16)(pk.w >> 16));
}
__device__ __forceinline__ void store8bf(u16* p, const float* v) {
    uint4 pk;
    pk.x = (u32)f2bf(v[0]) | ((u32)f2bf(v[1]) << 16);
    pk.y = (u32)f2bf(v[2]) | ((u32)f2bf(v[3]) << 16);
    pk.z = (u32)f2bf(v[4]) | ((u32)f2bf(v[5]) << 16);
    pk.w = (u32)f2bf(v[6]) | ((u32)f2bf(v[7]) << 16);
    *(uint4*)p = pk;
}

// ---------- fused prep: [0,196) bin edges | [196,196+4688) cvt_x | last cvt_w ----------
__global__ __launch_bounds__(256) void k_prep(const int* __restrict__ srcs,
                                              const int* __restrict__ dsts,
                                              int* __restrict__ bucket_cursor,
                                              u32* __restrict__ bucket_data,
                                              const float* __restrict__ x,
                                              u16* __restrict__ xb,
                                              const float* __restrict__ W1,
                                              const float* __restrict__ W2,
                                              u16* __restrict__ W1t,
                                              u16* __restrict__ W2t) {
    __shared__ int s_hist[256];
    __shared__ int s_base[256];
    __shared__ int s_cur[256];
    __shared__ int s_gbase[256];
    __shared__ u32 s_sorted[P1E];
    __shared__ unsigned char s_bkt[P1E];
    int t = threadIdx.x;
    int blk = blockIdx.x;
    if (blk >= NBK) {
        int cb = blk - NBK;
        if (cb < NB_CVTX) {
            int i = (cb * 256 + t) * 8;
            if (i < NN * FIN) {
                float4 f0 = *(const float4*)(x + i);
                float4 f1 = *(const float4*)(x + i + 4);
                ushort4 o0 = {f2bf(f0.x), f2bf(f0.y), f2bf(f0.z), f2bf(f0.w)};
                ushort4 o1 = {f2bf(f1.x), f2bf(f1.y), f2bf(f1.z), f2bf(f1.w)};
                *(ushort4*)(xb + i) = o0;
                *(ushort4*)(xb + i + 4) = o1;
            }
        } else {
            for (int i = t; i < FH * FIN + FC * FH; i += 256) {
                if (i < FH * FIN) {                   // W1t[128][96] from W1[96][128]
                    int n = i / FIN, k = i % FIN;
                    W1t[i] = f2bf(W1[k * FH + n]);
                } else {                              // W2t[64][128] from W2[128][64]
                    int j = i - FH * FIN;
                    int n = j / FH, k = j % FH;
                    W2t[j] = f2bf(W2[k * FC + n]);
                }
            }
        }
        return;
    }
    int e0 = blk * P1E;
    int n = NE - e0; if (n > P1E) n = P1E;
    s_hist[t] = 0;
    __syncthreads();
    u32 rp[16]; int rb[16];
#pragma unroll
    for (int j = 0; j < 16; j++) {
        int i = j * 256 + t;
        rb[j] = -1;
        if (i < n) {
            int s = srcs[e0 + i], d = dsts[e0 + i];
            int b = d >> BLOW;
            rb[j] = b;
            rp[j] = ((u32)(d & ((1 << BLOW) - 1)) << 17) | (u32)s;
            atomicAdd(&s_hist[b], 1);
        }
    }
    __syncthreads();
    int ct = s_hist[t];
    s_base[t] = ct;
    __syncthreads();
    for (int off = 1; off < 256; off <<= 1) {
        int v = (t >= off) ? s_base[t - off] : 0;
        __syncthreads();
        s_base[t] += v;
        __syncthreads();
    }
    int excl = s_base[t] - ct;
    __syncthreads();
    s_base[t] = excl;
    s_cur[t] = excl;
    if (t < NBK) s_gbase[t] = (ct > 0) ? atomicAdd(&bucket_cursor[t], ct) : 0;
    __syncthreads();
#pragma unroll
    for (int j = 0; j < 16; j++) {
        if (rb[j] >= 0) {
            int r = atomicAdd(&s_cur[rb[j]], 1);
            s_sorted[r] = rp[j];
            s_bkt[r] = (unsigned char)rb[j];
        }
    }
    __syncthreads();
    for (int i = t; i < n; i += 256) {
        int b = s_bkt[i];
        int gpos = s_gbase[b] + (i - s_base[b]);
        if (gpos < BCAP)
            bucket_data[(size_t)b * BCAP + gpos] = s_sorted[i];
    }
}

// ---------- per-bucket counting sort -> CSR + row_start + dinv + xb pre-scale ----------
__global__ __launch_bounds__(256) void k_csr(const int* __restrict__ bucket_cursor,
                                             const u32* __restrict__ bucket_data,
                                             int* __restrict__ row_start,
                                             float* __restrict__ dinv,
                                             int* __restrict__ src_sorted,
                                             u16* __restrict__ xb) {
    __shared__ int s_c[256];
    __shared__ int s_cnt[512];
    __shared__ int s_ps[256];
    __shared__ int s_off[512];
    __shared__ int s_cur[512];
    __shared__ float s_dinv[512];
    __shared__ u32 s_edges[BCAP];
    int t = threadIdx.x;
    int b = blockIdx.x;
    int nbe = bucket_cursor[b];
    if (nbe > BCAP) nbe = BCAP;
    s_c[t] = (t < NBK) ? bucket_cursor[t] : 0;
    __syncthreads();
    for (int off = 1; off < 256; off <<= 1) {
        int v = (t >= off) ? s_c[t - off] : 0;
        __syncthreads();
        s_c[t] += v;
        __syncthreads();
    }
    int bbase = s_c[b] - nbe;
    s_cnt[t] = 0; s_cnt[t + 256] = 0;
    __syncthreads();
    for (int i = t; i < nbe; i += 256) {
        u32 p = bucket_data[(size_t)b * BCAP + i];
        s_edges[i] = p;
        atomicAdd(&s_cnt[p >> 17], 1);
    }
    __syncthreads();
    int c0 = s_cnt[2 * t], c1 = s_cnt[2 * t + 1];
    s_ps[t] = c0 + c1;
    __syncthreads();
    for (int off = 1; off < 256; off <<= 1) {
        int v = (t >= off) ? s_ps[t - off] : 0;
        __syncthreads();
        s_ps[t] += v;
        __syncthreads();
    }
    int pexcl = s_ps[t] - (c0 + c1);
    s_off[2 * t] = pexcl;          s_cur[2 * t] = pexcl;
    s_off[2 * t + 1] = pexcl + c0; s_cur[2 * t + 1] = pexcl + c0;
    __syncthreads();
#pragma unroll
    for (int k = 0; k < 2; k++) {
        int ld = k * 256 + t;
        int gd = b * 512 + ld;
        if (gd < NN) {
            float dv = rsqrtf((float)s_cnt[ld] + 1.0f);
            row_start[gd] = bbase + s_off[ld];
            dinv[gd] = dv;
            s_dinv[ld] = dv;
        }
    }
    if (b == 0 && t == 0) row_start[NN] = NE;
    __syncthreads();
    // scatter within L2-resident region
    for (int i = t; i < nbe; i += 256) {
        u32 p = s_edges[i];
        int d = p >> 17;
        int r = atomicAdd(&s_cur[d], 1);
        src_sorted[bbase + r] = (int)(p & 0x1FFFFu);
    }
    // pre-scale this bucket's xb rows by dinv (in place)
    for (int i = t; i < 512 * 12; i += 256) {
        int r = i / 12, c = i % 12;
        int gd = b * 512 + r;
        if (gd < NN) {
            float dv = s_dinv[r];
            float v[8];
            u16* p = xb + (size_t)gd * FIN + c * 8;
            load8f(p, v);
#pragma unroll
            for (int j = 0; j < 8; j++) v[j] *= dv;
            store8bf(p, v);
        }
    }
}

// ---------- aggregation layer 1: rows pre-scaled, pure adds, unroll-4 ----------
__global__ void k_agg1(const u16* __restrict__ xb, const float* __restrict__ dinv,
                       const int* __restrict__ row_start, const int* __restrict__ src_sorted,
                       u16* __restrict__ aggx) {
    int tid = blockIdx.x * 256 + threadIdx.x;
    int dst = tid / 12, q = tid % 12;  // 12 chunks of 8 bf16 = 96 feats
    if (dst >= NN) return;
    int rs = row_start[dst], re = row_start[dst + 1];
    float dv = dinv[dst];
    float acc[8], v0[8], v1[8], v2[8], v3[8];
    load8f(xb + (size_t)dst * FIN + q * 8, acc);  // xs[dst] = dinv[dst]*x[dst]
    int e = rs;
    for (; e + 3 < re; e += 4) {
        int s0 = src_sorted[e], s1 = src_sorted[e + 1];
        int s2 = src_sorted[e + 2], s3 = src_sorted[e + 3];
        load8f(xb + (size_t)s0 * FIN + q * 8, v0);
        load8f(xb + (size_t)s1 * FIN + q * 8, v1);
        load8f(xb + (size_t)s2 * FIN + q * 8, v2);
        load8f(xb + (size_t)s3 * FIN + q * 8, v3);
#pragma unroll
        for (int j = 0; j < 8; j++) acc[j] += (v0[j] + v1[j]) + (v2[j] + v3[j]);
    }
    for (; e < re; e++) {
        int s0 = src_sorted[e];
        load8f(xb + (size_t)s0 * FIN + q * 8, v0);
#pragma unroll
        for (int j = 0; j < 8; j++) acc[j] += v0[j];
    }
#pragma unroll
    for (int j = 0; j < 8; j++) acc[j] *= dv;
    store8bf(aggx + (size_t)dst * FIN + q * 8, acc);
}

// ---------- fused GEMM1+GEMM2: emb = relu(aggx@W1+b1) [fp32], zb = dinv*(emb@W2) [bf16] ----------
#define LDSW 136  // 128 + 8 pad (16B-aligned rows, <=4-way ds_read_b128 conflict)
__global__ __launch_bounds__(128) void k_gemm12(const u16* __restrict__ aggx,
                                                const u16* __restrict__ W1t,
                                                const float* __restrict__ b1,
                                                const u16* __restrict__ W2t,
                                                const float* __restrict__ dinv,
                                                float* __restrict__ emb,
                                                u16* __restrict__ zb) {
    __shared__ u16 sh[2][16 * LDSW];
    int wid = threadIdx.x >> 6, lane = threadIdx.x & 63;
    int wave = blockIdx.x * 2 + wid;
    int row0 = wave << 4;
    int m = lane & 15, quad = lane >> 4;
    f32x4 acc[8] = {{0,0,0,0},{0,0,0,0},{0,0,0,0},{0,0,0,0},
                    {0,0,0,0},{0,0,0,0},{0,0,0,0},{0,0,0,0}};
#pragma unroll
    for (int kt = 0; kt < 3; kt++) {
        bf16x8 a = *(const bf16x8*)(const void*)(aggx + (size_t)(row0 + m) * FIN + kt * 32 + quad * 8);
#pragma unroll
        for (int nt = 0; nt < 8; nt++) {
            bf16x8 b = *(const bf16x8*)(const void*)(W1t + (size_t)(nt * 16 + m) * FIN + kt * 32 + quad * 8);
            acc[nt] = __builtin_amdgcn_mfma_f32_16x16x32_bf16(a, b, acc[nt], 0, 0, 0);
        }
    }
    u16* tile = sh[wid];
#pragma unroll
    for (int nt = 0; nt < 8; nt++) {
        int c = nt * 16 + m;
        float bias = b1[c];
#pragma unroll
        for (int i = 0; i < 4; i++) {
            int r = quad * 4 + i;
            float val = acc[nt][i] + bias;
            val = val > 0.0f ? val : 0.0f;
            emb[(size_t)(row0 + r) * FH + c] = val;
            tile[r * LDSW + c] = f2bf(val);
        }
    }
    float dvr[4];
#pragma unroll
    for (int i = 0; i < 4; i++) dvr[i] = dinv[row0 + quad * 4 + i];
    __syncthreads();
    f32x4 zacc[4] = {{0,0,0,0},{0,0,0,0},{0,0,0,0},{0,0,0,0}};
#pragma unroll
    for (int kt = 0; kt < 4; kt++) {
        bf16x8 a = *(const bf16x8*)(const void*)(tile + m * LDSW + kt * 32 + quad * 8);
#pragma unroll
        for (int nt = 0; nt < 4; nt++) {
            bf16x8 b = *(const bf16x8*)(const void*)(W2t + (size_t)(nt * 16 + m) * FH + kt * 32 + quad * 8);
            zacc[nt] = __builtin_amdgcn_mfma_f32_16x16x32_bf16(a, b, zacc[nt], 0, 0, 0);
        }
    }
#pragma unroll
    for (int nt = 0; nt < 4; nt++) {
        int c = nt * 16 + m;
#pragma unroll
        for (int i = 0; i < 4; i++) {
            int r = row0 + quad * 4 + i;
            zb[(size_t)r * FC + c] = f2bf(zacc[nt][i] * dvr[i]);  // pre-scaled by dinv[r]
        }
    }
}

// ---------- fused agg layer 2 + bias + log_softmax: thread-per-(dst, 8-chunk), unroll-4 ----------
__global__ void k_agg2lsm(const u16* __restrict__ zb, const float* __restrict__ dinv,
                          const int* __restrict__ row_start, const int* __restrict__ src_sorted,
                          const float* __restrict__ b2, float* __restrict__ logits) {
    int tid = blockIdx.x * 256 + threadIdx.x;
    int dst = tid >> 3, q = tid & 7;
    if (dst >= NN) return;
    int rs = row_start[dst], re = row_start[dst + 1];
    float dv = dinv[dst];
    float acc[8], v0[8], v1[8], v2[8], v3[8];
    load8f(zb + (size_t)dst * FC + q * 8, acc);  // zs[dst] = dinv[dst]*z[dst]
    int e = rs;
    for (; e + 3 < re; e += 4) {
        int s0 = src_sorted[e], s1 = src_sorted[e + 1];
        int s2 = src_sorted[e + 2], s3 = src_sorted[e + 3];
        load8f(zb + (size_t)s0 * FC + q * 8, v0);
        load8f(zb + (size_t)s1 * FC + q * 8, v1);
        load8f(zb + (size_t)s2 * FC + q * 8, v2);
        load8f(zb + (size_t)s3 * FC + q * 8, v3);
#pragma unroll
        for (int j = 0; j < 8; j++) acc[j] += (v0[j] + v1[j]) + (v2[j] + v3[j]);
    }
    for (; e < re; e++) {
        int s0 = src_sorted[e];
        load8f(zb + (size_t)s0 * FC + q * 8, v0);
#pragma unroll
        for (int j = 0; j < 8; j++) acc[j] += v0[j];
    }
#pragma unroll
    for (int j = 0; j < 8; j++) acc[j] = acc[j] * dv + b2[q * 8 + j];
    // log-softmax over 64 = 8 local + 8 lanes
    float mx = acc[0];
#pragma unroll
    for (int j = 1; j < 8; j++) mx = fmaxf(mx, acc[j]);
#pragma unroll
    for (int d = 1; d < 8; d <<= 1) mx = fmaxf(mx, __shfl_xor(mx, d, 64));
    float s = 0.0f;
#pragma unroll
    for (int j = 0; j < 8; j++) s += expf(acc[j] - mx);
#pragma unroll
    for (int d = 1; d < 8; d <<= 1) s += __shfl_xor(s, d, 64);
    float lse = mx + logf(s);
    float4 o0 = {acc[0] - lse, acc[1] - lse, acc[2] - lse, acc[3] - lse};
    float4 o1 = {acc[4] - lse, acc[5] - lse, acc[6] - lse, acc[7] - lse};
    *(float4*)(logits + (size_t)dst * FC + q * 8) = o0;
    *(float4*)(logits + (size_t)dst * FC + q * 8 + 4) = o1;
}

extern "C" void kernel_launch(void* const* d_in, const int* in_sizes, int n_in,
                              void* d_out, int out_size, void* d_ws, size_t ws_size,
                              hipStream_t stream) {
    const float* x  = (const float*)d_in[0];
    const float* W1 = (const float*)d_in[1];
    const float* b1 = (const float*)d_in[2];
    const float* W2 = (const float*)d_in[3];
    const float* b2 = (const float*)d_in[4];
    const int* ei   = (const int*)d_in[5];
    const int* srcs = ei;
    const int* dsts = ei + NE;

    float* logits = (float*)d_out;                    // [N,64]
    float* emb    = (float*)d_out + (size_t)NN * FC;  // [N,128] fp32

    char* w = (char*)d_ws;
    float* dinv       = (float*)w; w += 400000;
    int*   row_start  = (int*)w;   w += 400128;  // N+1 ints, padded
    int*   src_sorted = (int*)w;   w += 3200000;
    int*   bucket_cursor = (int*)w; w += 1024;
    u16*   xb         = (u16*)w;   w += 19200000;
    u16*   aggx       = (u16*)w;   w += 19200000;
    u16*   W1t        = (u16*)w;   w += 24576;
    u16*   W2t        = (u16*)w;   w += 16384;
    u16*   zb         = (u16*)w;   w += 12800000;
    // bucket_data overlays aggx (dead before k_agg1 writes aggx)
    u32*   bucket_data = (u32*)aggx;

    hipMemsetAsync(bucket_cursor, 0, NBK * 4, stream);
    k_prep<<<NBK + NB_CVTX + 1, 256, 0, stream>>>(srcs, dsts, bucket_cursor, bucket_data,
                                                  x, xb, W1, W2, W1t, W2t);
    k_csr<<<NBK, 256, 0, stream>>>(bucket_cursor, bucket_data, row_start, dinv, src_sorted, xb);
    k_agg1<<<(NN * 12 + 255) / 256, 256, 0, stream>>>(xb, dinv, row_start, src_sorted, aggx);
    k_gemm12<<<NN / 32, 128, 0, stream>>>(aggx, W1t, b1, W2t, dinv, emb, zb);
    k_agg2lsm<<<(NN * 8 + 255) / 256, 256, 0, stream>>>(zb, dinv, row_start, src_sorted, b2, logits);
}

// Round 6
// 227.486 us; speedup vs baseline: 1.0076x; 1.0076x over previous
//
#include <hip/hip_runtime.h>
#include <hip/hip_bf16.h>

#define NN 100000
#define NE 800000
#define FIN 96
#define FH 128
#define FC 64

#define BLOW 9            // 512 dsts per bucket
#define NBK 196           // ceil(NN/512)
#define BCAP 5120         // bucket capacity (avg 4096, sd ~64)
#define P1E 4096          // edges per bin block
#define NB_CVTX ((NN * FIN / 8 + 255) / 256)   // 4688 (8 floats/thread)

typedef unsigned short u16;
typedef unsigned int u32;
typedef __attribute__((ext_vector_type(8))) __bf16 bf16x8;
typedef __attribute__((ext_vector_type(4))) float f32x4;

__device__ __forceinline__ float bf2f(u16 u) {
    u32 x = ((u32)u) << 16;
    return __builtin_bit_cast(float, x);
}
__device__ __forceinline__ u16 f2bf(float f) {
    u32 u = __builtin_bit_cast(u32, f);
    u += 0x7fffu + ((u >> 16) & 1u);
    return (u16)(u >> 16);
}
__device__ __forceinline__ void load8f(const u16* p, float* o) {
    uint4 pk = *(const uint4*)p;
    o[0] = bf2f((u16)pk.x); o[1] = bf2f((u16)(pk.x >> 16));
    o[2] = bf2f((u16)pk.y); o[3] = bf2f((u16)(pk.y >> 16));
    o[4] = bf2f((u16)pk.z); o[5] = bf2f((u16)(pk.z >> 16));
    o[6] = bf2f((u16)pk.w); o[7] = bf2f((u16)(pk.w >> 16));
}
__device__ __forceinline__ void store8bf(u16* p, const float* v) {
    uint4 pk;
    pk.x = (u32)f2bf(v[0]) | ((u32)f2bf(v[1]) << 16);
    pk.y = (u32)f2bf(v[2]) | ((u32)f2bf(v[3]) << 16);
    pk.z = (u32)f2bf(v[4]) | ((u32)f2bf(v[5]) << 16);
    pk.w = (u32)f2bf(v[6]) | ((u32)f2bf(v[7]) << 16);
    *(uint4*)p = pk;
}

// ---------- fused prep: [0,196) bin edges | [196,196+4688) cvt_x | last cvt_w ----------
__global__ __launch_bounds__(256) void k_prep(const int* __restrict__ srcs,
                                              const int* __restrict__ dsts,
                                              int* __restrict__ bucket_cursor,
                                              u32* __restrict__ bucket_data,
                                              const float* __restrict__ x,
                                              u16* __restrict__ xb,
                                              const float* __restrict__ W1,
                                              const float* __restrict__ W2,
                                              u16* __restrict__ W1t,
                                              u16* __restrict__ W2t) {
    __shared__ int s_hist[256];
    __shared__ int s_base[256];
    __shared__ int s_cur[256];
    __shared__ int s_gbase[256];
    __shared__ u32 s_sorted[P1E];
    __shared__ unsigned char s_bkt[P1E];
    int t = threadIdx.x;
    int blk = blockIdx.x;
    if (blk >= NBK) {
        int cb = blk - NBK;
        if (cb < NB_CVTX) {
            int i = (cb * 256 + t) * 8;
            if (i < NN * FIN) {
                float4 f0 = *(const float4*)(x + i);
                float4 f1 = *(const float4*)(x + i + 4);
                ushort4 o0 = {f2bf(f0.x), f2bf(f0.y), f2bf(f0.z), f2bf(f0.w)};
                ushort4 o1 = {f2bf(f1.x), f2bf(f1.y), f2bf(f1.z), f2bf(f1.w)};
                *(ushort4*)(xb + i) = o0;
                *(ushort4*)(xb + i + 4) = o1;
            }
        } else {
            for (int i = t; i < FH * FIN + FC * FH; i += 256) {
                if (i < FH * FIN) {                   // W1t[128][96] from W1[96][128]
                    int n = i / FIN, k = i % FIN;
                    W1t[i] = f2bf(W1[k * FH + n]);
                } else {                              // W2t[64][128] from W2[128][64]
                    int j = i - FH * FIN;
                    int n = j / FH, k = j % FH;
                    W2t[j] = f2bf(W2[k * FC + n]);
                }
            }
        }
        return;
    }
    int e0 = blk * P1E;
    int n = NE - e0; if (n > P1E) n = P1E;
    s_hist[t] = 0;
    __syncthreads();
    u32 rp[16]; int rb[16];
#pragma unroll
    for (int j = 0; j < 16; j++) {
        int i = j * 256 + t;
        rb[j] = -1;
        if (i < n) {
            int s = srcs[e0 + i], d = dsts[e0 + i];
            int b = d >> BLOW;
            rb[j] = b;
            rp[j] = ((u32)(d & ((1 << BLOW) - 1)) << 17) | (u32)s;
            atomicAdd(&s_hist[b], 1);
        }
    }
    __syncthreads();
    int ct = s_hist[t];
    s_base[t] = ct;
    __syncthreads();
    for (int off = 1; off < 256; off <<= 1) {
        int v = (t >= off) ? s_base[t - off] : 0;
        __syncthreads();
        s_base[t] += v;
        __syncthreads();
    }
    int excl = s_base[t] - ct;
    __syncthreads();
    s_base[t] = excl;
    s_cur[t] = excl;
    if (t < NBK) s_gbase[t] = (ct > 0) ? atomicAdd(&bucket_cursor[t], ct) : 0;
    __syncthreads();
#pragma unroll
    for (int j = 0; j < 16; j++) {
        if (rb[j] >= 0) {
            int r = atomicAdd(&s_cur[rb[j]], 1);
            s_sorted[r] = rp[j];
            s_bkt[r] = (unsigned char)rb[j];
        }
    }
    __syncthreads();
    for (int i = t; i < n; i += 256) {
        int b = s_bkt[i];
        int gpos = s_gbase[b] + (i - s_base[b]);
        if (gpos < BCAP)
            bucket_data[(size_t)b * BCAP + gpos] = s_sorted[i];
    }
}

// ---------- per-bucket counting sort -> CSR + row_start + dinv ----------
__global__ __launch_bounds__(256) void k_csr(const int* __restrict__ bucket_cursor,
                                             const u32* __restrict__ bucket_data,
                                             int* __restrict__ row_start,
                                             float* __restrict__ dinv,
                                             int* __restrict__ src_sorted) {
    __shared__ int s_c[256];
    __shared__ int s_cnt[512];
    __shared__ int s_ps[256];
    __shared__ int s_off[512];
    __shared__ int s_cur[512];
    __shared__ u32 s_edges[BCAP];
    int t = threadIdx.x;
    int b = blockIdx.x;
    int nbe = bucket_cursor[b];
    if (nbe > BCAP) nbe = BCAP;
    s_c[t] = (t < NBK) ? bucket_cursor[t] : 0;
    __syncthreads();
    for (int off = 1; off < 256; off <<= 1) {
        int v = (t >= off) ? s_c[t - off] : 0;
        __syncthreads();
        s_c[t] += v;
        __syncthreads();
    }
    int bbase = s_c[b] - nbe;
    s_cnt[t] = 0; s_cnt[t + 256] = 0;
    __syncthreads();
    for (int i = t; i < nbe; i += 256) {
        u32 p = bucket_data[(size_t)b * BCAP + i];
        s_edges[i] = p;
        atomicAdd(&s_cnt[p >> 17], 1);
    }
    __syncthreads();
    int c0 = s_cnt[2 * t], c1 = s_cnt[2 * t + 1];
    s_ps[t] = c0 + c1;
    __syncthreads();
    for (int off = 1; off < 256; off <<= 1) {
        int v = (t >= off) ? s_ps[t - off] : 0;
        __syncthreads();
        s_ps[t] += v;
        __syncthreads();
    }
    int pexcl = s_ps[t] - (c0 + c1);
    s_off[2 * t] = pexcl;          s_cur[2 * t] = pexcl;
    s_off[2 * t + 1] = pexcl + c0; s_cur[2 * t + 1] = pexcl + c0;
    __syncthreads();
#pragma unroll
    for (int k = 0; k < 2; k++) {
        int ld = k * 256 + t;
        int gd = b * 512 + ld;
        if (gd < NN) {
            row_start[gd] = bbase + s_off[ld];
            dinv[gd] = rsqrtf((float)s_cnt[ld] + 1.0f);
        }
    }
    if (b == 0 && t == 0) row_start[NN] = NE;
    __syncthreads();
    for (int i = t; i < nbe; i += 256) {
        u32 p = s_edges[i];
        int d = p >> 17;
        int r = atomicAdd(&s_cur[d], 1);
        src_sorted[bbase + r] = (int)(p & 0x1FFFFu);
    }
}

// ---------- fused agg1 + GEMM1 + GEMM2 ----------
// Block = 128 thr (2 waves) = 32 dst rows. Phase 1: gather-aggregate x rows into
// LDS A-tile [16][96] (stride 104). Phase 2: per-wave MFMA GEMM1 -> relu -> emb +
// LDS h-tile -> MFMA GEMM2 -> zb (pre-scaled by dinv[row]).
#define ATW 104   // 96 + 8 pad, 16B-aligned rows
#define LDSW 136  // 128 + 8 pad
__global__ __launch_bounds__(128) void k_ag1gemm(const u16* __restrict__ xb,
                                                 const float* __restrict__ dinv,
                                                 const int* __restrict__ row_start,
                                                 const int* __restrict__ src_sorted,
                                                 const u16* __restrict__ W1t,
                                                 const float* __restrict__ b1,
                                                 const u16* __restrict__ W2t,
                                                 float* __restrict__ emb,
                                                 u16* __restrict__ zb) {
    __shared__ u16 atile[2][16 * ATW];
    __shared__ u16 htile[2][16 * LDSW];
    int t = threadIdx.x;
    int wid = t >> 6, lane = t & 63;
    int row0 = blockIdx.x << 5;          // 32 rows per block
    // ---- phase 1: aggregate 32 dsts x 12 chunks = 384 items over 128 threads ----
    for (int it = t; it < 384; it += 128) {
        int dl = it / 12, q = it % 12;
        int dst = row0 + dl;
        int rs = row_start[dst], re = row_start[dst + 1];
        float dv = dinv[dst];
        float acc[8], v0[8], v1[8];
        load8f(xb + (size_t)dst * FIN + q * 8, acc);
#pragma unroll
        for (int j = 0; j < 8; j++) acc[j] *= dv;   // self-loop dinv[d]*x[d]
        int e = rs;
        for (; e + 1 < re; e += 2) {
            int s0 = src_sorted[e], s1 = src_sorted[e + 1];
            float d0 = dinv[s0], d1 = dinv[s1];
            load8f(xb + (size_t)s0 * FIN + q * 8, v0);
            load8f(xb + (size_t)s1 * FIN + q * 8, v1);
#pragma unroll
            for (int j = 0; j < 8; j++) acc[j] += v0[j] * d0 + v1[j] * d1;
        }
        if (e < re) {
            int s0 = src_sorted[e];
            float d0 = dinv[s0];
            load8f(xb + (size_t)s0 * FIN + q * 8, v0);
#pragma unroll
            for (int j = 0; j < 8; j++) acc[j] += v0[j] * d0;
        }
#pragma unroll
        for (int j = 0; j < 8; j++) acc[j] *= dv;
        store8bf(&atile[dl >> 4][(dl & 15) * ATW + q * 8], acc);
    }
    __syncthreads();
    // ---- phase 2: per-wave GEMMs ----
    int m = lane & 15, quad = lane >> 4;
    int wrow0 = row0 + (wid << 4);
    const u16* at = atile[wid];
    f32x4 acc[8] = {{0,0,0,0},{0,0,0,0},{0,0,0,0},{0,0,0,0},
                    {0,0,0,0},{0,0,0,0},{0,0,0,0},{0,0,0,0}};
#pragma unroll
    for (int kt = 0; kt < 3; kt++) {
        bf16x8 a = *(const bf16x8*)(const void*)(at + m * ATW + kt * 32 + quad * 8);
#pragma unroll
        for (int nt = 0; nt < 8; nt++) {
            bf16x8 b = *(const bf16x8*)(const void*)(W1t + (size_t)(nt * 16 + m) * FIN + kt * 32 + quad * 8);
            acc[nt] = __builtin_amdgcn_mfma_f32_16x16x32_bf16(a, b, acc[nt], 0, 0, 0);
        }
    }
    u16* tile = htile[wid];
#pragma unroll
    for (int nt = 0; nt < 8; nt++) {
        int c = nt * 16 + m;
        float bias = b1[c];
#pragma unroll
        for (int i = 0; i < 4; i++) {
            int r = quad * 4 + i;
            float val = acc[nt][i] + bias;
            val = val > 0.0f ? val : 0.0f;
            emb[(size_t)(wrow0 + r) * FH + c] = val;
            tile[r * LDSW + c] = f2bf(val);
        }
    }
    float dvr[4];
#pragma unroll
    for (int i = 0; i < 4; i++) dvr[i] = dinv[wrow0 + quad * 4 + i];
    __syncthreads();
    f32x4 zacc[4] = {{0,0,0,0},{0,0,0,0},{0,0,0,0},{0,0,0,0}};
#pragma unroll
    for (int kt = 0; kt < 4; kt++) {
        bf16x8 a = *(const bf16x8*)(const void*)(tile + m * LDSW + kt * 32 + quad * 8);
#pragma unroll
        for (int nt = 0; nt < 4; nt++) {
            bf16x8 b = *(const bf16x8*)(const void*)(W2t + (size_t)(nt * 16 + m) * FH + kt * 32 + quad * 8);
            zacc[nt] = __builtin_amdgcn_mfma_f32_16x16x32_bf16(a, b, zacc[nt], 0, 0, 0);
        }
    }
#pragma unroll
    for (int nt = 0; nt < 4; nt++) {
        int c = nt * 16 + m;
#pragma unroll
        for (int i = 0; i < 4; i++) {
            int r = wrow0 + quad * 4 + i;
            zb[(size_t)r * FC + c] = f2bf(zacc[nt][i] * dvr[i]);  // zb = dinv[r]*z[r]
        }
    }
}

// ---------- fused agg layer 2 + bias + log_softmax: thread-per-(dst, 8-chunk) ----------
// zb rows pre-scaled by dinv -> edge loop is pure adds.
__global__ void k_agg2lsm(const u16* __restrict__ zb, const float* __restrict__ dinv,
                          const int* __restrict__ row_start, const int* __restrict__ src_sorted,
                          const float* __restrict__ b2, float* __restrict__ logits) {
    int tid = blockIdx.x * 256 + threadIdx.x;
    int dst = tid >> 3, q = tid & 7;
    if (dst >= NN) return;
    int rs = row_start[dst], re = row_start[dst + 1];
    float dv = dinv[dst];
    float acc[8], v0[8], v1[8], v2[8], v3[8];
    load8f(zb + (size_t)dst * FC + q * 8, acc);  // = dinv[dst]*z[dst]
    int e = rs;
    for (; e + 3 < re; e += 4) {
        int s0 = src_sorted[e], s1 = src_sorted[e + 1];
        int s2 = src_sorted[e + 2], s3 = src_sorted[e + 3];
        load8f(zb + (size_t)s0 * FC + q * 8, v0);
        load8f(zb + (size_t)s1 * FC + q * 8, v1);
        load8f(zb + (size_t)s2 * FC + q * 8, v2);
        load8f(zb + (size_t)s3 * FC + q * 8, v3);
#pragma unroll
        for (int j = 0; j < 8; j++) acc[j] += (v0[j] + v1[j]) + (v2[j] + v3[j]);
    }
    for (; e < re; e++) {
        int s0 = src_sorted[e];
        load8f(zb + (size_t)s0 * FC + q * 8, v0);
#pragma unroll
        for (int j = 0; j < 8; j++) acc[j] += v0[j];
    }
#pragma unroll
    for (int j = 0; j < 8; j++) acc[j] = acc[j] * dv + b2[q * 8 + j];
    float mx = acc[0];
#pragma unroll
    for (int j = 1; j < 8; j++) mx = fmaxf(mx, acc[j]);
#pragma unroll
    for (int d = 1; d < 8; d <<= 1) mx = fmaxf(mx, __shfl_xor(mx, d, 64));
    float s = 0.0f;
#pragma unroll
    for (int j = 0; j < 8; j++) s += expf(acc[j] - mx);
#pragma unroll
    for (int d = 1; d < 8; d <<= 1) s += __shfl_xor(s, d, 64);
    float lse = mx + logf(s);
    float4 o0 = {acc[0] - lse, acc[1] - lse, acc[2] - lse, acc[3] - lse};
    float4 o1 = {acc[4] - lse, acc[5] - lse, acc[6] - lse, acc[7] - lse};
    *(float4*)(logits + (size_t)dst * FC + q * 8) = o0;
    *(float4*)(logits + (size_t)dst * FC + q * 8 + 4) = o1;
}

extern "C" void kernel_launch(void* const* d_in, const int* in_sizes, int n_in,
                              void* d_out, int out_size, void* d_ws, size_t ws_size,
                              hipStream_t stream) {
    const float* x  = (const float*)d_in[0];
    const float* W1 = (const float*)d_in[1];
    const float* b1 = (const float*)d_in[2];
    const float* W2 = (const float*)d_in[3];
    const float* b2 = (const float*)d_in[4];
    const int* ei   = (const int*)d_in[5];
    const int* srcs = ei;
    const int* dsts = ei + NE;

    float* logits = (float*)d_out;                    // [N,64]
    float* emb    = (float*)d_out + (size_t)NN * FC;  // [N,128] fp32

    char* w = (char*)d_ws;
    float* dinv       = (float*)w; w += 400000;
    int*   row_start  = (int*)w;   w += 400128;  // N+1 ints, padded
    int*   src_sorted = (int*)w;   w += 3200000;
    int*   bucket_cursor = (int*)w; w += 1024;
    u16*   xb         = (u16*)w;   w += 19200000;
    u16*   W1t        = (u16*)w;   w += 24576;
    u16*   W2t        = (u16*)w;   w += 16384;
    u16*   zb         = (u16*)w;   w += 12800000;
    u16*   bdws       = (u16*)w;   w += 4014080;  // bucket_data 196*5120*4 B
    u32*   bucket_data = (u32*)bdws;

    hipMemsetAsync(bucket_cursor, 0, NBK * 4, stream);
    k_prep<<<NBK + NB_CVTX + 1, 256, 0, stream>>>(srcs, dsts, bucket_cursor, bucket_data,
                                                  x, xb, W1, W2, W1t, W2t);
    k_csr<<<NBK, 256, 0, stream>>>(bucket_cursor, bucket_data, row_start, dinv, src_sorted);
    k_ag1gemm<<<NN / 32, 128, 0, stream>>>(xb, dinv, row_start, src_sorted, W1t, b1, W2t, emb, zb);
    k_agg2lsm<<<(NN * 8 + 255) / 256, 256, 0, stream>>>(zb, dinv, row_start, src_sorted, b2, logits);
}

// Round 7
// 219.996 us; speedup vs baseline: 1.0419x; 1.0341x over previous
//
#include <hip/hip_runtime.h>
#include <hip/hip_bf16.h>

#define NN 100000
#define NE 800000
#define FIN 96
#define FH 128
#define FC 64

#define BLOW 9            // 512 dsts per bucket
#define NBK 196           // ceil(NN/512)
#define BCAP 5120         // bucket capacity (avg 4096, sd ~64)
#define P1E 4096          // edges per bin block
#define NB_CVTX ((NN * FIN / 8 + 255) / 256)   // 4688 (8 floats/thread)

typedef unsigned short u16;
typedef unsigned int u32;
typedef __attribute__((ext_vector_type(8))) __bf16 bf16x8;
typedef __attribute__((ext_vector_type(4))) float f32x4;

__device__ __forceinline__ float bf2f(u16 u) {
    u32 x = ((u32)u) << 16;
    return __builtin_bit_cast(float, x);
}
__device__ __forceinline__ u16 f2bf(float f) {
    u32 u = __builtin_bit_cast(u32, f);
    u += 0x7fffu + ((u >> 16) & 1u);
    return (u16)(u >> 16);
}
__device__ __forceinline__ void load8f(const u16* p, float* o) {
    uint4 pk = *(const uint4*)p;
    o[0] = bf2f((u16)pk.x); o[1] = bf2f((u16)(pk.x >> 16));
    o[2] = bf2f((u16)pk.y); o[3] = bf2f((u16)(pk.y >> 16));
    o[4] = bf2f((u16)pk.z); o[5] = bf2f((u16)(pk.z >> 16));
    o[6] = bf2f((u16)pk.w); o[7] = bf2f((u16)(pk.w >> 16));
}
__device__ __forceinline__ void store8bf(u16* p, const float* v) {
    uint4 pk;
    pk.x = (u32)f2bf(v[0]) | ((u32)f2bf(v[1]) << 16);
    pk.y = (u32)f2bf(v[2]) | ((u32)f2bf(v[3]) << 16);
    pk.z = (u32)f2bf(v[4]) | ((u32)f2bf(v[5]) << 16);
    pk.w = (u32)f2bf(v[6]) | ((u32)f2bf(v[7]) << 16);
    *(uint4*)p = pk;
}

// ---------- fused prep: [0,196) bin edges | [196,196+4688) cvt_x | last cvt_w ----------
__global__ __launch_bounds__(256) void k_prep(const int* __restrict__ srcs,
                                              const int* __restrict__ dsts,
                                              int* __restrict__ bucket_cursor,
                                              u32* __restrict__ bucket_data,
                                              const float* __restrict__ x,
                                              u16* __restrict__ xb,
                                              const float* __restrict__ W1,
                                              const float* __restrict__ W2,
                                              u16* __restrict__ W1t,
                                              u16* __restrict__ W2t) {
    __shared__ int s_hist[256];
    __shared__ int s_base[256];
    __shared__ int s_cur[256];
    __shared__ int s_gbase[256];
    __shared__ u32 s_sorted[P1E];
    __shared__ unsigned char s_bkt[P1E];
    int t = threadIdx.x;
    int blk = blockIdx.x;
    if (blk >= NBK) {
        int cb = blk - NBK;
        if (cb < NB_CVTX) {
            int i = (cb * 256 + t) * 8;
            if (i < NN * FIN) {
                float4 f0 = *(const float4*)(x + i);
                float4 f1 = *(const float4*)(x + i + 4);
                ushort4 o0 = {f2bf(f0.x), f2bf(f0.y), f2bf(f0.z), f2bf(f0.w)};
                ushort4 o1 = {f2bf(f1.x), f2bf(f1.y), f2bf(f1.z), f2bf(f1.w)};
                *(ushort4*)(xb + i) = o0;
                *(ushort4*)(xb + i + 4) = o1;
            }
        } else {
            for (int i = t; i < FH * FIN + FC * FH; i += 256) {
                if (i < FH * FIN) {                   // W1t[128][96] from W1[96][128]
                    int n = i / FIN, k = i % FIN;
                    W1t[i] = f2bf(W1[k * FH + n]);
                } else {                              // W2t[64][128] from W2[128][64]
                    int j = i - FH * FIN;
                    int n = j / FH, k = j % FH;
                    W2t[j] = f2bf(W2[k * FC + n]);
                }
            }
        }
        return;
    }
    int e0 = blk * P1E;
    int n = NE - e0; if (n > P1E) n = P1E;
    s_hist[t] = 0;
    __syncthreads();
    u32 rp[16]; int rb[16];
#pragma unroll
    for (int j = 0; j < 16; j++) {
        int i = j * 256 + t;
        rb[j] = -1;
        if (i < n) {
            int s = srcs[e0 + i], d = dsts[e0 + i];
            int b = d >> BLOW;
            rb[j] = b;
            rp[j] = ((u32)(d & ((1 << BLOW) - 1)) << 17) | (u32)s;
            atomicAdd(&s_hist[b], 1);
        }
    }
    __syncthreads();
    int ct = s_hist[t];
    s_base[t] = ct;
    __syncthreads();
    for (int off = 1; off < 256; off <<= 1) {
        int v = (t >= off) ? s_base[t - off] : 0;
        __syncthreads();
        s_base[t] += v;
        __syncthreads();
    }
    int excl = s_base[t] - ct;
    __syncthreads();
    s_base[t] = excl;
    s_cur[t] = excl;
    if (t < NBK) s_gbase[t] = (ct > 0) ? atomicAdd(&bucket_cursor[t], ct) : 0;
    __syncthreads();
#pragma unroll
    for (int j = 0; j < 16; j++) {
        if (rb[j] >= 0) {
            int r = atomicAdd(&s_cur[rb[j]], 1);
            s_sorted[r] = rp[j];
            s_bkt[r] = (unsigned char)rb[j];
        }
    }
    __syncthreads();
    for (int i = t; i < n; i += 256) {
        int b = s_bkt[i];
        int gpos = s_gbase[b] + (i - s_base[b]);
        if (gpos < BCAP)
            bucket_data[(size_t)b * BCAP + gpos] = s_sorted[i];
    }
}

// ---------- per-bucket counting sort -> CSR + row_start + dinv ----------
__global__ __launch_bounds__(256) void k_csr(const int* __restrict__ bucket_cursor,
                                             const u32* __restrict__ bucket_data,
                                             int* __restrict__ row_start,
                                             float* __restrict__ dinv,
                                             int* __restrict__ src_sorted) {
    __shared__ int s_c[256];
    __shared__ int s_cnt[512];
    __shared__ int s_ps[256];
    __shared__ int s_off[512];
    __shared__ int s_cur[512];
    __shared__ u32 s_edges[BCAP];
    int t = threadIdx.x;
    int b = blockIdx.x;
    int nbe = bucket_cursor[b];
    if (nbe > BCAP) nbe = BCAP;
    s_c[t] = (t < NBK) ? bucket_cursor[t] : 0;
    __syncthreads();
    for (int off = 1; off < 256; off <<= 1) {
        int v = (t >= off) ? s_c[t - off] : 0;
        __syncthreads();
        s_c[t] += v;
        __syncthreads();
    }
    int bbase = s_c[b] - nbe;
    s_cnt[t] = 0; s_cnt[t + 256] = 0;
    __syncthreads();
    for (int i = t; i < nbe; i += 256) {
        u32 p = bucket_data[(size_t)b * BCAP + i];
        s_edges[i] = p;
        atomicAdd(&s_cnt[p >> 17], 1);
    }
    __syncthreads();
    int c0 = s_cnt[2 * t], c1 = s_cnt[2 * t + 1];
    s_ps[t] = c0 + c1;
    __syncthreads();
    for (int off = 1; off < 256; off <<= 1) {
        int v = (t >= off) ? s_ps[t - off] : 0;
        __syncthreads();
        s_ps[t] += v;
        __syncthreads();
    }
    int pexcl = s_ps[t] - (c0 + c1);
    s_off[2 * t] = pexcl;          s_cur[2 * t] = pexcl;
    s_off[2 * t + 1] = pexcl + c0; s_cur[2 * t + 1] = pexcl + c0;
    __syncthreads();
#pragma unroll
    for (int k = 0; k < 2; k++) {
        int ld = k * 256 + t;
        int gd = b * 512 + ld;
        if (gd < NN) {
            row_start[gd] = bbase + s_off[ld];
            dinv[gd] = rsqrtf((float)s_cnt[ld] + 1.0f);
        }
    }
    if (b == 0 && t == 0) row_start[NN] = NE;
    __syncthreads();
    for (int i = t; i < nbe; i += 256) {
        u32 p = s_edges[i];
        int d = p >> 17;
        int r = atomicAdd(&s_cur[d], 1);
        src_sorted[bbase + r] = (int)(p & 0x1FFFFu);
    }
}

// ---------- aggregation layer 1: thread-per-(dst, 12-chunk), unroll-4, per-edge dinv ----------
__global__ void k_agg1(const u16* __restrict__ xb, const float* __restrict__ dinv,
                       const int* __restrict__ row_start, const int* __restrict__ src_sorted,
                       u16* __restrict__ aggx) {
    int tid = blockIdx.x * 256 + threadIdx.x;
    int dst = tid / 12, q = tid % 12;  // 12 chunks of 8 bf16 = 96 feats
    if (dst >= NN) return;
    int rs = row_start[dst], re = row_start[dst + 1];
    float dv = dinv[dst];
    float acc[8], v0[8], v1[8], v2[8], v3[8];
    load8f(xb + (size_t)dst * FIN + q * 8, acc);
#pragma unroll
    for (int j = 0; j < 8; j++) acc[j] *= dv;  // self-loop term
    int e = rs;
    for (; e + 3 < re; e += 4) {
        int s0 = src_sorted[e], s1 = src_sorted[e + 1];
        int s2 = src_sorted[e + 2], s3 = src_sorted[e + 3];
        float d0 = dinv[s0], d1 = dinv[s1], d2 = dinv[s2], d3 = dinv[s3];
        load8f(xb + (size_t)s0 * FIN + q * 8, v0);
        load8f(xb + (size_t)s1 * FIN + q * 8, v1);
        load8f(xb + (size_t)s2 * FIN + q * 8, v2);
        load8f(xb + (size_t)s3 * FIN + q * 8, v3);
#pragma unroll
        for (int j = 0; j < 8; j++)
            acc[j] += (v0[j] * d0 + v1[j] * d1) + (v2[j] * d2 + v3[j] * d3);
    }
    for (; e < re; e++) {
        int s0 = src_sorted[e];
        float d0 = dinv[s0];
        load8f(xb + (size_t)s0 * FIN + q * 8, v0);
#pragma unroll
        for (int j = 0; j < 8; j++) acc[j] += v0[j] * d0;
    }
#pragma unroll
    for (int j = 0; j < 8; j++) acc[j] *= dv;
    store8bf(aggx + (size_t)dst * FIN + q * 8, acc);
}

// ---------- fused GEMM1+GEMM2: emb = relu(aggx@W1+b1) [fp32], zb = dinv*(emb@W2) [bf16] ----------
#define LDSW 136  // 128 + 8 pad (16B-aligned rows, <=4-way ds_read_b128 conflict)
__global__ __launch_bounds__(128) void k_gemm12(const u16* __restrict__ aggx,
                                                const u16* __restrict__ W1t,
                                                const float* __restrict__ b1,
                                                const u16* __restrict__ W2t,
                                                const float* __restrict__ dinv,
                                                float* __restrict__ emb,
                                                u16* __restrict__ zb) {
    __shared__ u16 sh[2][16 * LDSW];
    int wid = threadIdx.x >> 6, lane = threadIdx.x & 63;
    int wave = blockIdx.x * 2 + wid;
    int row0 = wave << 4;
    int m = lane & 15, quad = lane >> 4;
    f32x4 acc[8] = {{0,0,0,0},{0,0,0,0},{0,0,0,0},{0,0,0,0},
                    {0,0,0,0},{0,0,0,0},{0,0,0,0},{0,0,0,0}};
#pragma unroll
    for (int kt = 0; kt < 3; kt++) {
        bf16x8 a = *(const bf16x8*)(const void*)(aggx + (size_t)(row0 + m) * FIN + kt * 32 + quad * 8);
#pragma unroll
        for (int nt = 0; nt < 8; nt++) {
            bf16x8 b = *(const bf16x8*)(const void*)(W1t + (size_t)(nt * 16 + m) * FIN + kt * 32 + quad * 8);
            acc[nt] = __builtin_amdgcn_mfma_f32_16x16x32_bf16(a, b, acc[nt], 0, 0, 0);
        }
    }
    u16* tile = sh[wid];
#pragma unroll
    for (int nt = 0; nt < 8; nt++) {
        int c = nt * 16 + m;
        float bias = b1[c];
#pragma unroll
        for (int i = 0; i < 4; i++) {
            int r = quad * 4 + i;
            float val = acc[nt][i] + bias;
            val = val > 0.0f ? val : 0.0f;
            emb[(size_t)(row0 + r) * FH + c] = val;
            tile[r * LDSW + c] = f2bf(val);
        }
    }
    float dvr[4];
#pragma unroll
    for (int i = 0; i < 4; i++) dvr[i] = dinv[row0 + quad * 4 + i];
    __syncthreads();
    f32x4 zacc[4] = {{0,0,0,0},{0,0,0,0},{0,0,0,0},{0,0,0,0}};
#pragma unroll
    for (int kt = 0; kt < 4; kt++) {
        bf16x8 a = *(const bf16x8*)(const void*)(tile + m * LDSW + kt * 32 + quad * 8);
#pragma unroll
        for (int nt = 0; nt < 4; nt++) {
            bf16x8 b = *(const bf16x8*)(const void*)(W2t + (size_t)(nt * 16 + m) * FH + kt * 32 + quad * 8);
            zacc[nt] = __builtin_amdgcn_mfma_f32_16x16x32_bf16(a, b, zacc[nt], 0, 0, 0);
        }
    }
#pragma unroll
    for (int nt = 0; nt < 4; nt++) {
        int c = nt * 16 + m;
#pragma unroll
        for (int i = 0; i < 4; i++) {
            int r = row0 + quad * 4 + i;
            zb[(size_t)r * FC + c] = f2bf(zacc[nt][i] * dvr[i]);  // zb = dinv[r]*z[r]
        }
    }
}

// ---------- fused agg layer 2 + bias + log_softmax: thread-per-(dst, 8-chunk) ----------
// zb rows pre-scaled by dinv -> edge loop is pure adds.
__global__ void k_agg2lsm(const u16* __restrict__ zb, const float* __restrict__ dinv,
                          const int* __restrict__ row_start, const int* __restrict__ src_sorted,
                          const float* __restrict__ b2, float* __restrict__ logits) {
    int tid = blockIdx.x * 256 + threadIdx.x;
    int dst = tid >> 3, q = tid & 7;
    if (dst >= NN) return;
    int rs = row_start[dst], re = row_start[dst + 1];
    float dv = dinv[dst];
    float acc[8], v0[8], v1[8], v2[8], v3[8];
    load8f(zb + (size_t)dst * FC + q * 8, acc);  // = dinv[dst]*z[dst]
    int e = rs;
    for (; e + 3 < re; e += 4) {
        int s0 = src_sorted[e], s1 = src_sorted[e + 1];
        int s2 = src_sorted[e + 2], s3 = src_sorted[e + 3];
        load8f(zb + (size_t)s0 * FC + q * 8, v0);
        load8f(zb + (size_t)s1 * FC + q * 8, v1);
        load8f(zb + (size_t)s2 * FC + q * 8, v2);
        load8f(zb + (size_t)s3 * FC + q * 8, v3);
#pragma unroll
        for (int j = 0; j < 8; j++) acc[j] += (v0[j] + v1[j]) + (v2[j] + v3[j]);
    }
    for (; e < re; e++) {
        int s0 = src_sorted[e];
        load8f(zb + (size_t)s0 * FC + q * 8, v0);
#pragma unroll
        for (int j = 0; j < 8; j++) acc[j] += v0[j];
    }
#pragma unroll
    for (int j = 0; j < 8; j++) acc[j] = acc[j] * dv + b2[q * 8 + j];
    float mx = acc[0];
#pragma unroll
    for (int j = 1; j < 8; j++) mx = fmaxf(mx, acc[j]);
#pragma unroll
    for (int d = 1; d < 8; d <<= 1) mx = fmaxf(mx, __shfl_xor(mx, d, 64));
    float s = 0.0f;
#pragma unroll
    for (int j = 0; j < 8; j++) s += expf(acc[j] - mx);
#pragma unroll
    for (int d = 1; d < 8; d <<= 1) s += __shfl_xor(s, d, 64);
    float lse = mx + logf(s);
    float4 o0 = {acc[0] - lse, acc[1] - lse, acc[2] - lse, acc[3] - lse};
    float4 o1 = {acc[4] - lse, acc[5] - lse, acc[6] - lse, acc[7] - lse};
    *(float4*)(logits + (size_t)dst * FC + q * 8) = o0;
    *(float4*)(logits + (size_t)dst * FC + q * 8 + 4) = o1;
}

extern "C" void kernel_launch(void* const* d_in, const int* in_sizes, int n_in,
                              void* d_out, int out_size, void* d_ws, size_t ws_size,
                              hipStream_t stream) {
    const float* x  = (const float*)d_in[0];
    const float* W1 = (const float*)d_in[1];
    const float* b1 = (const float*)d_in[2];
    const float* W2 = (const float*)d_in[3];
    const float* b2 = (const float*)d_in[4];
    const int* ei   = (const int*)d_in[5];
    const int* srcs = ei;
    const int* dsts = ei + NE;

    float* logits = (float*)d_out;                    // [N,64]
    float* emb    = (float*)d_out + (size_t)NN * FC;  // [N,128] fp32

    char* w = (char*)d_ws;
    float* dinv       = (float*)w; w += 400000;
    int*   row_start  = (int*)w;   w += 400128;  // N+1 ints, padded
    int*   src_sorted = (int*)w;   w += 3200000;
    int*   bucket_cursor = (int*)w; w += 1024;
    u16*   xb         = (u16*)w;   w += 19200000;
    u16*   aggx       = (u16*)w;   w += 19200000;
    u16*   W1t        = (u16*)w;   w += 24576;
    u16*   W2t        = (u16*)w;   w += 16384;
    u16*   zb         = (u16*)w;   w += 12800000;
    // bucket_data overlays aggx (dead before k_agg1 writes aggx)
    u32*   bucket_data = (u32*)aggx;

    hipMemsetAsync(bucket_cursor, 0, NBK * 4, stream);
    k_prep<<<NBK + NB_CVTX + 1, 256, 0, stream>>>(srcs, dsts, bucket_cursor, bucket_data,
                                                  x, xb, W1, W2, W1t, W2t);
    k_csr<<<NBK, 256, 0, stream>>>(bucket_cursor, bucket_data, row_start, dinv, src_sorted);
    k_agg1<<<(NN * 12 + 255) / 256, 256, 0, stream>>>(xb, dinv, row_start, src_sorted, aggx);
    k_gemm12<<<NN / 32, 128, 0, stream>>>(aggx, W1t, b1, W2t, dinv, emb, zb);
    k_agg2lsm<<<(NN * 8 + 255) / 256, 256, 0, stream>>>(zb, dinv, row_start, src_sorted, b2, logits);
}